// Round 11
// baseline (43.042 us; speedup 1.0000x reference)
//
#include <hip/hip_runtime.h>
#include <cfloat>
#include <cstdint>

// Problem constants (SHAPE=(96,128,128), B=2, C=32, two maxpool(K3,S2,P1) layers)
// Composed pooling: window 7, stride 4, pad 3. Output grid 2 x 24 x 32 x 32 x 32.
#define B_    2
#define OD    24
#define OH    32
#define OW    32
#define NC    32
#define NBINS (B_ * OD * OH * OW)   // 49152
#define RSTRIDE 16                  // record slots per bin
#define OVF_CAP 100000
#define SCAN_T 1024
#define CHUNK  (NBINS / SCAN_T)

// tile geometry: 4 x 4 x 4 output cells per workgroup
#define TZ 4
#define TY 4
#define TX 4
#define TCELLS 64
#define NTZ (OD/TZ)                 // 6
#define NTY (OH/TY)                 // 8
#define NTX (OW/TX)                 // 8
#define NTILES (B_*NTZ*NTY*NTX)     // 768 = 3 blocks/CU
#define NBZ (TZ+1)
#define NBY (TY+1)
#define NBX (TX+1)
#define NB  (NBZ*NBY*NBX)           // 125
#define CELLCAP 64                  // pairs per cell (mean ~21.8, Poisson-safe)
#define SOVF_CAP 1024               // per-tile spill list (expected empty)

// ---------------- binning (unchanged, proven) ----------------

__global__ __launch_bounds__(256) void k_bin(const int* __restrict__ coors,
                                             int* __restrict__ counts,
                                             int* __restrict__ records,
                                             int* __restrict__ ovf_n,
                                             int2* __restrict__ ovf, int N) {
    int i = blockIdx.x * blockDim.x + threadIdx.x;
    if (i >= N) return;
    int4 cc = reinterpret_cast<const int4*>(coors)[i];   // b, z, y, x
    int bin = (((cc.x * OD + (cc.y >> 2)) * OH + (cc.z >> 2)) * OW + (cc.w >> 2));
    // bit k (k = lz + 2*ly + 4*lx): point qualifies for cell bin+(lz,ly,lx)
    int mask = 0xFF;
    if (!(cc.y & 3)) mask &= 0x55;
    if (!(cc.z & 3)) mask &= 0x33;
    if (!(cc.w & 3)) mask &= 0x0F;
    int rec = (i << 8) | mask;   // mask bit0 always set -> rec != 0
    int pos = atomicAdd(&counts[bin], 1);
    if (pos < RSTRIDE) {
        records[bin * RSTRIDE + pos] = rec;
    } else {
        int o = atomicAdd(ovf_n, 1);
        if (o < OVF_CAP) ovf[o] = make_int2(bin, rec);
    }
}

// expand one record's set bits into per-cell pair lists
__device__ __forceinline__ void push_rec(int rec, int fm, int cb,
                                         int* cellcnt, int* celllist,
                                         int2* sovf, int* sovf_n) {
    int idx = (int)(((unsigned)rec) >> 8);
    while (fm) {
        int k = __builtin_ctz(fm); fm &= fm - 1;
        int cell = cb + ((k & 1) << 4) + (((k >> 1) & 1) << 2) + ((k >> 2) & 1);
        int pos = atomicAdd(&cellcnt[cell], 1);
        if (pos < CELLCAP) celllist[cell * CELLCAP + pos] = idx;
        else { int o = atomicAdd(sovf_n, 1);
               if (o < SOVF_CAP) sovf[o] = make_int2(cell, idx); }
    }
}

// ---------------- tile: per-cell pair lists + register-fmax gather ----------
// one block per 4x4x4-cell tile; gather thread = (cellgroup cg = tid>>5, ch = tid&31)

__global__ __launch_bounds__(512) void k_tile(const float* __restrict__ feat,
                                              const int* __restrict__ counts,
                                              const int* __restrict__ records,
                                              const int* __restrict__ ovf_n,
                                              const int2* __restrict__ ovf,
                                              float* __restrict__ out) {
    __shared__ int  cellcnt[TCELLS];              // 256 B
    __shared__ int  celllist[TCELLS * CELLCAP];   // 16 KB
    __shared__ int2 sovf[SOVF_CAP];               // 8 KB
    __shared__ int  sovf_n;

    // XCD-aware swizzle (768 % 8 == 0 -> bijective): per-XCD feat slab ~3.2MB
    // stays L2-resident -- matters now that feat rows are read per-pair.
    const int t   = (blockIdx.x & 7) * (NTILES / 8) + (blockIdx.x >> 3);
    const int tid = threadIdx.x;
    const int tx_ = t & (NTX - 1);
    const int ty_ = (t >> 3) & (NTY - 1);
    const int rest = t >> 6;                   // b*NTZ + tz, 0..11
    const int b   = (rest >= NTZ) ? 1 : 0;
    const int tz_ = rest - b * NTZ;
    const int tz0 = tz_ * TZ, ty0 = ty_ * TY, tx0 = tx_ * TX;

    if (tid < TCELLS) cellcnt[tid] = 0;
    if (tid == 0) sovf_n = 0;
    __syncthreads();

    // ---- build per-cell pair lists: FOUR threads per neighborhood bin ----
    if (tid < 4 * NB) {                        // 500 threads
        int bn  = tid >> 2;                    // bin 0..124
        int sl  = tid & 3;                     // record quad 0..3
        int rz  = bn / (NBY * NBX);
        int rem = bn - rz * (NBY * NBX);
        int ry  = rem / NBX;
        int rx  = rem - ry * NBX;
        int bz = tz0 - 1 + rz, by = ty0 - 1 + ry, bx = tx0 - 1 + rx;
        if ((bz | by | bx) >= 0) {             // upper side in-grid by tiling
            int bin = ((b * OD + bz) * OH + by) * OW + bx;
            int cnt = counts[bin]; if (cnt > RSTRIDE) cnt = RSTRIDE;
            int4 q = *(const int4*)(records + bin * RSTRIDE + sl * 4);
            int bi = rz - 1, bj = ry - 1, bl = rx - 1;
            int vm = 0xFF;                     // tile-validity mask per k
            if (bi < 0) vm &= 0xAA;  if (bi > TZ - 2) vm &= 0x55;
            if (bj < 0) vm &= 0xCC;  if (bj > TY - 2) vm &= 0x33;
            if (bl < 0) vm &= 0xF0;  if (bl > TX - 2) vm &= 0x0F;
            int cb = bi * (TY * TX) + bj * TX + bl;
            int rs0 = sl << 2;
            int f0 = (rs0 + 0 < cnt) ? (q.x & vm & 0xFF) : 0;
            int f1 = (rs0 + 1 < cnt) ? (q.y & vm & 0xFF) : 0;
            int f2 = (rs0 + 2 < cnt) ? (q.z & vm & 0xFF) : 0;
            int f3 = (rs0 + 3 < cnt) ? (q.w & vm & 0xFF) : 0;
            if (f0) push_rec(q.x, f0, cb, cellcnt, celllist, sovf, &sovf_n);
            if (f1) push_rec(q.y, f1, cb, cellcnt, celllist, sovf, &sovf_n);
            if (f2) push_rec(q.z, f2, cb, cellcnt, celllist, sovf, &sovf_n);
            if (f3) push_rec(q.w, f3, cb, cellcnt, celllist, sovf, &sovf_n);
        }
    }

    // ---- global overflow net (expected empty) ----
    int on = *ovf_n;
    if (on > 0 && tid == 0) {
        if (on > OVF_CAP) on = OVF_CAP;
        for (int e = 0; e < on; ++e) {
            int2 ov = ovf[e];
            int bx = ov.x & (OW - 1);
            int by = (ov.x >> 5) & (OH - 1);
            int rest2 = ov.x >> 10;            // b*OD + bz
            int bb = (rest2 >= OD) ? 1 : 0;
            int bz = rest2 - bb * OD;
            if (bb != b) continue;
            int rz = bz - (tz0 - 1), ry = by - (ty0 - 1), rx = bx - (tx0 - 1);
            if (rz < 0 || rz >= NBZ || ry < 0 || ry >= NBY || rx < 0 || rx >= NBX) continue;
            int bi = rz - 1, bj = ry - 1, bl = rx - 1;
            int vm = 0xFF;
            if (bi < 0) vm &= 0xAA;  if (bi > TZ - 2) vm &= 0x55;
            if (bj < 0) vm &= 0xCC;  if (bj > TY - 2) vm &= 0x33;
            if (bl < 0) vm &= 0xF0;  if (bl > TX - 2) vm &= 0x0F;
            int fm = ov.y & vm & 0xFF;
            if (fm) push_rec(ov.y, fm, bi * (TY * TX) + bj * TX + bl,
                             cellcnt, celllist, sovf, &sovf_n);
        }
    }
    __syncthreads();

    // ---- gather: 4 cells per thread, register fmax, no atomics/branches ----
    const int cg = tid >> 5;       // cell group 0..15 (cells cg*4 .. cg*4+3)
    const int ch = tid & 31;
    float m0 = -FLT_MAX, m1 = -FLT_MAX, m2 = -FLT_MAX, m3 = -FLT_MAX;
    int n0, n1, n2, n3;

#define GATHER(MV, NV, CELL) do {                                           \
    int nn = cellcnt[CELL]; NV = nn; if (nn > CELLCAP) nn = CELLCAP;        \
    const int* L = &celllist[(CELL) * CELLCAP];                             \
    for (int j = 0; j < nn; j += 4) {                                       \
        int4 iq = *(const int4*)&L[j];                                      \
        int i1 = (j + 1 < nn) ? iq.y : iq.x;   /* dup index: harmless max */\
        int i2 = (j + 2 < nn) ? iq.z : iq.x;                                \
        int i3 = (j + 3 < nn) ? iq.w : iq.x;                                \
        float f0 = feat[(unsigned)iq.x * NC + ch];                          \
        float f1 = feat[(unsigned)i1 * NC + ch];                            \
        float f2 = feat[(unsigned)i2 * NC + ch];                            \
        float f3 = feat[(unsigned)i3 * NC + ch];                            \
        MV = fmaxf(MV, fmaxf(fmaxf(f0, f1), fmaxf(f2, f3)));                \
    } } while (0)

    GATHER(m0, n0, cg * 4 + 0);
    GATHER(m1, n1, cg * 4 + 1);
    GATHER(m2, n2, cg * 4 + 2);
    GATHER(m3, n3, cg * 4 + 3);
#undef GATHER

    // ---- per-tile spill scan (normally zero-trip) ----
    int son = sovf_n; if (son > SOVF_CAP) son = SOVF_CAP;
    for (int j = 0; j < son; ++j) {
        int2 e = sovf[j];
        float f = feat[(unsigned)e.y * NC + ch];
        if (e.x == cg * 4 + 0) m0 = fmaxf(m0, f);
        else if (e.x == cg * 4 + 1) m1 = fmaxf(m1, f);
        else if (e.x == cg * 4 + 2) m2 = fmaxf(m2, f);
        else if (e.x == cg * 4 + 3) m3 = fmaxf(m3, f);
    }

    // ---- epilogue: registers -> global, coalesced 128B per half-wave ----
#define WRITE(MV, NV, CELL) do {                                            \
    int iz = (CELL) >> 4, iy = ((CELL) >> 2) & 3, ix = (CELL) & 3;          \
    size_t o = ((((size_t)(b * OD + tz0 + iz)) * OH + (ty0 + iy)) * OW      \
               + (tx0 + ix)) * NC + ch;                                     \
    out[o] = (NV > 0) ? MV : 0.0f; } while (0)

    WRITE(m0, n0, cg * 4 + 0);
    WRITE(m1, n1, cg * 4 + 1);
    WRITE(m2, n2, cg * 4 + 2);
    WRITE(m3, n3, cg * 4 + 3);
#undef WRITE
}

// ================= fallback path (scan-based, small ws) =====================

__global__ void k_hist(const int* __restrict__ coors, int* __restrict__ counts, int N) {
    int i = blockIdx.x * blockDim.x + threadIdx.x;
    if (i >= N) return;
    int4 cc = reinterpret_cast<const int4*>(coors)[i];
    int bin = (((cc.x * OD + (cc.y >> 2)) * OH + (cc.z >> 2)) * OW + (cc.w >> 2));
    atomicAdd(&counts[bin], 1);
}

__global__ void k_scan(const int* __restrict__ counts,
                       int2* __restrict__ binfo,
                       int* __restrict__ cursor) {
    __shared__ int lds[SCAN_T];
    int t = threadIdx.x;
    int base = t * CHUNK;
    int s = 0;
#pragma unroll
    for (int k = 0; k < CHUNK; ++k) s += counts[base + k];
    lds[t] = s;
    __syncthreads();
    for (int d = 1; d < SCAN_T; d <<= 1) {
        int v = (t >= d) ? lds[t - d] : 0;
        __syncthreads();
        lds[t] += v;
        __syncthreads();
    }
    int excl = (t == 0) ? 0 : lds[t - 1];
    for (int k = 0; k < CHUNK; ++k) {
        int i = base + k;
        int c = counts[i];
        binfo[i] = make_int2(excl, c);
        cursor[i] = excl;
        excl += c;
    }
}

__global__ void k_place(const int* __restrict__ coors, int* __restrict__ cursor,
                        int* __restrict__ records, int N) {
    int i = blockIdx.x * blockDim.x + threadIdx.x;
    if (i >= N) return;
    int4 cc = reinterpret_cast<const int4*>(coors)[i];
    int bin = (((cc.x * OD + (cc.y >> 2)) * OH + (cc.z >> 2)) * OW + (cc.w >> 2));
    int pos = atomicAdd(&cursor[bin], 1);
    records[pos] = (i << 6) | (cc.y & 3) | ((cc.z & 3) << 2) | ((cc.w & 3) << 4);
}

__global__ __launch_bounds__(256) void k_gather_fb(const float4* __restrict__ feat4,
                                                   const int2* __restrict__ binfo,
                                                   const int* __restrict__ records,
                                                   float4* __restrict__ out4, int N) {
    int tid  = blockIdx.x * blockDim.x + threadIdx.x;
    int wid  = tid >> 6;
    int lane = threadIdx.x & 63;
    int q    = lane >> 3;
    int cq   = lane & 7;

    int ox  = wid & (OW - 1);
    int oy  = (wid >> 5) & (OH - 1);
    int bzc = wid >> 10;
    int b   = (bzc >= OD) ? 1 : 0;
    int oz  = bzc - b * OD;

    int2 bi[8];
#pragma unroll
    for (int k = 0; k < 8; ++k) {
        const int lz = k & 1, ly = (k >> 1) & 1, lx = (k >> 2) & 1;
        int z2 = oz - lz, y2 = oy - ly, x2 = ox - lx;
        bool okbin = ((z2 | y2 | x2) >= 0);
        int bin = ((b * OD + z2) * OH + y2) * OW + x2;
        int2 v = binfo[okbin ? bin : 0];
        if (!okbin) { v.x = N; v.y = 0; }
        bi[k] = v;
    }

    int recs[8];
#pragma unroll
    for (int k = 0; k < 8; ++k) {
        int j = (q < bi[k].y) ? q : 0;
        recs[k] = records[bi[k].x + j];
    }

    float4 m = make_float4(-FLT_MAX, -FLT_MAX, -FLT_MAX, -FLT_MAX);
    int any = 0;
#pragma unroll
    for (int k = 0; k < 8; ++k) {
        int rec = recs[k];
        bool ok = (q < bi[k].y);
        if (k & 1) ok = ok && ((rec & 3)  != 0);
        if (k & 2) ok = ok && ((rec & 12) != 0);
        if (k & 4) ok = ok && ((rec & 48) != 0);
        if (ok) {
            float4 f = feat4[(rec >> 6) * (NC / 4) + cq];
            m.x = fmaxf(m.x, f.x); m.y = fmaxf(m.y, f.y);
            m.z = fmaxf(m.z, f.z); m.w = fmaxf(m.w, f.w);
            any = 1;
        }
    }

#pragma unroll
    for (int k = 0; k < 8; ++k) {
        for (int j0 = 8; j0 < bi[k].y; j0 += 8) {
            int j = j0 + q;
            bool ok = (j < bi[k].y);
            int rec = records[bi[k].x + (ok ? j : 0)];
            if (k & 1) ok = ok && ((rec & 3)  != 0);
            if (k & 2) ok = ok && ((rec & 12) != 0);
            if (k & 4) ok = ok && ((rec & 48) != 0);
            if (ok) {
                float4 f = feat4[(rec >> 6) * (NC / 4) + cq];
                m.x = fmaxf(m.x, f.x); m.y = fmaxf(m.y, f.y);
                m.z = fmaxf(m.z, f.z); m.w = fmaxf(m.w, f.w);
                any = 1;
            }
        }
    }

#pragma unroll
    for (int s = 8; s < 64; s <<= 1) {
        m.x = fmaxf(m.x, __shfl_xor(m.x, s, 64));
        m.y = fmaxf(m.y, __shfl_xor(m.y, s, 64));
        m.z = fmaxf(m.z, __shfl_xor(m.z, s, 64));
        m.w = fmaxf(m.w, __shfl_xor(m.w, s, 64));
    }
    bool active = (__ballot(any) != 0ULL);

    if (q == 0) {
        float4 z4 = make_float4(0.f, 0.f, 0.f, 0.f);
        out4[wid * (NC / 4) + cq] = active ? m : z4;
    }
}

// ---------------- launch ----------------

extern "C" void kernel_launch(void* const* d_in, const int* in_sizes, int n_in,
                              void* d_out, int out_size, void* d_ws, size_t ws_size,
                              hipStream_t stream) {
    const float* feat  = (const float*)d_in[0];
    const int*   coors = (const int*)d_in[1];
    const int N = in_sizes[0] / NC;          // 200000
    float* out = (float*)d_out;              // 1572864 floats

    const size_t fast_ints = (size_t)NBINS + 8 + (size_t)NBINS * RSTRIDE
                           + 2ull * OVF_CAP;
    if (ws_size >= fast_ints * sizeof(int)) {
        int*  counts  = (int*)d_ws;                     // NBINS
        int*  ovf_n   = counts + NBINS;                 // 1 (+7 pad)
        int*  records = counts + NBINS + 8;             // NBINS*16
        int2* ovf     = (int2*)(records + (size_t)NBINS * RSTRIDE);

        hipMemsetAsync(counts, 0, (NBINS + 8) * sizeof(int), stream);
        k_bin<<<(N + 255) / 256, 256, 0, stream>>>(coors, counts, records,
                                                   ovf_n, ovf, N);
        k_tile<<<NTILES, 512, 0, stream>>>(feat, counts, records,
                                           ovf_n, (const int2*)ovf, out);
    } else {
        // fallback: scan-based path, ~1.6 MB ws
        int*  counts  = (int*)d_ws;
        int2* binfo   = (int2*)(counts + NBINS);
        int*  cursor  = (int*)(binfo + NBINS);
        int*  records = cursor + NBINS;

        hipMemsetAsync(counts, 0, NBINS * sizeof(int), stream);
        k_hist <<<(N + 255) / 256, 256, 0, stream>>>(coors, counts, N);
        k_scan <<<1, SCAN_T, 0, stream>>>(counts, binfo, cursor);
        k_place<<<(N + 255) / 256, 256, 0, stream>>>(coors, cursor, records, N);
        k_gather_fb<<<(NBINS * 64) / 256, 256, 0, stream>>>(
            (const float4*)feat, (const int2*)binfo, records, (float4*)out, N);
    }
}